// Round 16
// baseline (152.966 us; speedup 1.0000x reference)
//
#include <hip/hip_runtime.h>
#include <hip/hip_bf16.h>
#include <cstdint>
#include <cstddef>

#define N_NODES 50000
#define N_EDGES 800000
#define DIM 64
#define N_REL 16
#define N_Q 8192
#define NKEY (N_NODES * 16)
#define KDIM 1088   // 16 relations * 64 + 64 self
#define SROW 1096   // padded LDS row in bf16 elems
#define TILE 16     // nodes per block (8 waves)
#define NKB 34      // K blocks of 32 (KDIM/32)
#define WTL (4 * NKB * 512)  // per-layer packed wt elems
#define NBKT 196    // coarse buckets (dst>>8)

// fused-prep grid partition
#define NB_PROJ 12500            // 50000*64/256
#define NB_WPREP 544             // 2*WTL/256
#define NB_BINA 196              // ceil(N_EDGES/4096)
#define NB_W1P 48                // 4*6*512/256
#define NB_REB 4                 // 1024/256

typedef __attribute__((ext_vector_type(8))) short bf16x8;
typedef __attribute__((ext_vector_type(4))) float f32x4;

__device__ __forceinline__ unsigned short f2bf(float f) {
    unsigned int b = __float_as_uint(f);
    return (unsigned short)((b + 0x7FFFu + ((b >> 16) & 1u)) >> 16);
}
__device__ __forceinline__ float bf2f(unsigned short u) {
    return __uint_as_float(((unsigned int)u) << 16);
}

// ---------- fused prep: input proj + wt pack + coarse hist + w1 pack + rel_emb bf16 ----------
__global__ __launch_bounds__(256) void k_prep(
    const float* __restrict__ nf, const float* __restrict__ inw,
    const float* __restrict__ inb, unsigned short* __restrict__ xbf,
    const float* __restrict__ rel_w, const float* __restrict__ self_w,
    unsigned short* __restrict__ wt, const int* __restrict__ dst,
    int* __restrict__ btot, const float* __restrict__ sc_w1,
    unsigned short* __restrict__ w1p, const float* __restrict__ rel_emb,
    unsigned short* __restrict__ reb)
{
    __shared__ int h[NBKT];
    const int b = blockIdx.x, tid = threadIdx.x;
    if (b < NB_PROJ) {
        int t = b * 256 + tid;
        int n = t >> 6, o = t & 63;
        float4 f = *reinterpret_cast<const float4*>(nf + (size_t)n * 4);
        float a = inb[o] + f.x * inw[o] + f.y * inw[64 + o] + f.z * inw[128 + o] + f.w * inw[192 + o];
        xbf[t] = f2bf(a > 0.f ? a : 0.f);
    } else if (b < NB_PROJ + NB_WPREP) {
        int i = (b - NB_PROJ) * 256 + tid;
        int j = i & 7;
        int lane = (i >> 3) & 63;
        int rest = i >> 9;          // l*136 + g*34 + t
        int t = rest % NKB;
        int gl = rest / NKB;
        int g = gl & 3;
        int l = gl >> 2;
        int col = g * 16 + (lane & 15);
        int k = t * 32 + (lane >> 4) * 8 + j;
        float v;
        if (k < 1024) {
            int r = k >> 6, d = k & 63;
            v = rel_w[(((size_t)l * 16 + r) * 64 + d) * 64 + col];
        } else {
            int d = k - 1024;
            v = self_w[((size_t)l * 64 + d) * 64 + col];
        }
        wt[i] = f2bf(v);
    } else if (b < NB_PROJ + NB_WPREP + NB_BINA) {
        // coarse per-bucket histogram (btot pre-zeroed via memset)
        const int t = tid;
        if (t < NBKT) h[t] = 0;
        __syncthreads();
        const int e0 = (b - NB_PROJ - NB_WPREP) * 4096;
        #pragma unroll
        for (int j = 0; j < 16; ++j) {
            int e = e0 + j * 256 + t;
            if (e < N_EDGES) atomicAdd(&h[dst[e] >> 8], 1);
        }
        __syncthreads();
        if (t < NBKT && h[t]) atomicAdd(&btot[t], h[t]);
    } else if (b < NB_PROJ + NB_WPREP + NB_BINA + NB_W1P) {
        int i = (b - NB_PROJ - NB_WPREP - NB_BINA) * 256 + tid;  // < 12288
        int j = i & 7;
        int lane = (i >> 3) & 63;
        int rest = i >> 9;          // g*6 + t, < 24
        int t = rest % 6;
        int g = rest / 6;
        int col = g * 16 + (lane & 15);
        int k = t * 32 + (lane >> 4) * 8 + j;   // < 192
        w1p[i] = f2bf(sc_w1[k * 64 + col]);
    } else {
        int i = (b - NB_PROJ - NB_WPREP - NB_BINA - NB_W1P) * 256 + tid;
        if (i < N_REL * 64) reb[i] = f2bf(rel_emb[i]);
    }
}

// ---------- bucket pipeline ----------
__global__ __launch_bounds__(256) void k_binS(
    const int* __restrict__ btot, int* __restrict__ bbase, int* __restrict__ gcur)
{
    const int t = threadIdx.x;
    int v = (t < NBKT) ? btot[t] : 0;
    const int lane = t & 63, wid = t >> 6;
    int incl = v;
    #pragma unroll
    for (int o = 1; o < 64; o <<= 1) { int u = __shfl_up(incl, o); if (lane >= o) incl += u; }
    __shared__ int ws[4];
    if (lane == 63) ws[wid] = incl;
    __syncthreads();
    int wb = 0;
    #pragma unroll
    for (int w = 0; w < 4; ++w) if (w < wid) wb += ws[w];
    int excl = wb + incl - v;
    if (t < NBKT) { bbase[t] = excl; gcur[t] = excl; }
    if (t == NBKT - 1) bbase[NBKT] = excl + v;
}

// payload = src<<12 | (dst&255)<<4 | et
__global__ __launch_bounds__(256) void k_binB(
    const int* __restrict__ src, const int* __restrict__ dst, const int* __restrict__ et,
    int* __restrict__ gcur, unsigned int* __restrict__ scratch)
{
    __shared__ int cnt[NBKT], base[NBKT], lcur[NBKT];
    const int t = threadIdx.x;
    if (t < NBKT) cnt[t] = 0;
    __syncthreads();
    const int e0 = blockIdx.x * 4096;
    int dv[16];
    #pragma unroll
    for (int j = 0; j < 16; ++j) {
        int e = e0 + j * 256 + t;
        dv[j] = (e < N_EDGES) ? dst[e] : -1;
        if (dv[j] >= 0) atomicAdd(&cnt[dv[j] >> 8], 1);
    }
    __syncthreads();
    if (t < NBKT) {
        base[t] = cnt[t] ? atomicAdd(&gcur[t], cnt[t]) : 0;
        lcur[t] = 0;
    }
    __syncthreads();
    #pragma unroll
    for (int j = 0; j < 16; ++j) {
        int e = e0 + j * 256 + t;
        if (dv[j] >= 0) {
            int b = dv[j] >> 8;
            int pos = base[b] + atomicAdd(&lcur[b], 1);
            unsigned p = ((unsigned)src[e] << 12) | ((unsigned)(dv[j] & 255) << 4) | (unsigned)et[e];
            scratch[pos] = p;
        }
    }
}

// pass K: per bucket: fine histogram + local scan -> offs; local scatter -> csr
// csr entry = (dst&15)<<28 | src<<7 | et   (node-local row in top nibble, TILE=16)
__global__ __launch_bounds__(1024) void k_key2(
    const int* __restrict__ bbase, const unsigned int* __restrict__ scratch,
    int* __restrict__ offs, unsigned int* __restrict__ csr)
{
    __shared__ int hist[4096];
    __shared__ int wsum[16];
    const int t = threadIdx.x;
    const int b = blockIdx.x;
    const int k0 = b * 4096;
    #pragma unroll
    for (int j = 0; j < 4; ++j) hist[t + j * 1024] = 0;
    __syncthreads();
    const int E0 = bbase[b], E1 = bbase[b + 1];
    for (int e = E0 + t; e < E1; e += 1024)
        atomicAdd(&hist[scratch[e] & 0xFFFu], 1);
    __syncthreads();
    int4 h4 = *reinterpret_cast<int4*>(&hist[t * 4]);
    int run = h4.x + h4.y + h4.z + h4.w;
    const int lane = t & 63, wid = t >> 6;
    int incl = run;
    #pragma unroll
    for (int o = 1; o < 64; o <<= 1) { int u = __shfl_up(incl, o); if (lane >= o) incl += u; }
    if (lane == 63) wsum[wid] = incl;
    __syncthreads();
    if (wid == 0) {
        int wv = (lane < 16) ? wsum[lane] : 0;
        #pragma unroll
        for (int o = 1; o < 16; o <<= 1) { int u = __shfl_up(wv, o); if (lane >= o) wv += u; }
        if (lane < 16) wsum[lane] = wv;
    }
    __syncthreads();
    int texcl = (wid ? wsum[wid - 1] : 0) + incl - run;
    int4 cur;
    cur.x = E0 + texcl;
    cur.y = cur.x + h4.x;
    cur.z = cur.y + h4.y;
    cur.w = cur.z + h4.z;
    *reinterpret_cast<int4*>(&hist[t * 4]) = cur;
    if (k0 + t * 4 < NKEY)
        *reinterpret_cast<int4*>(&offs[k0 + t * 4]) = cur;
    if (b == NBKT - 1 && t == 0) offs[NKEY] = N_EDGES;
    __syncthreads();
    for (int e = E0 + t; e < E1; e += 1024) {
        unsigned p = scratch[e];
        int pos = atomicAdd(&hist[p & 0xFFFu], 1);
        csr[pos] = (((p >> 4) & 15u) << 28) | ((p >> 12) << 7) | (p & 15u);
    }
}

// ---------- fused layer: 16 nodes/block, 8 waves, balanced edge-split gather ----------
__global__ __launch_bounds__(512, 8) void k_layer(
    const unsigned short* __restrict__ xbf_in,
    const int* __restrict__ offs,          // per (node,rel) key
    const unsigned int* __restrict__ csr,  // (nl<<28)|(src<<7)|et
    const unsigned short* __restrict__ wt, // this layer, packed: [4][34][64][8] bf16
    const float* __restrict__ selfb,       // [64]
    unsigned short* __restrict__ xbf_out)
{
    alignas(16) __shared__ unsigned short S[TILE * SROW];   // 35072 B
    __shared__ float invs[TILE];
    const int tid = threadIdx.x, lane = tid & 63;
    const int wid = __builtin_amdgcn_readfirstlane(tid >> 6);   // 0..7
    const int nb = blockIdx.x * TILE;

    // zero own 2 rows' rel region; write self slots + invs
    #pragma unroll
    for (int s = 0; s < 2; ++s) {
        const int nl = wid * 2 + s;
        unsigned int* Sr = reinterpret_cast<unsigned int*>(&S[nl * SROW]);
        #pragma unroll
        for (int i = 0; i < 8; ++i) Sr[lane + i * 64] = 0u;
        const int node = nb + nl;
        S[nl * SROW + 1024 + lane] = xbf_in[(size_t)node * 64 + lane];
        if (lane == 0) {
            int dg = offs[node * 16 + 16] - offs[node * 16];
            invs[nl] = 1.0f / (float)(dg > 1 ? dg : 1);
        }
    }
    const int E0 = offs[nb * 16];
    const int E1 = offs[(nb + TILE) * 16];
    __syncthreads();   // rows zeroed before any wave writes runs

    // phase A: balanced chunks; wave owns runs that START in its chunk
    {
        const int total = E1 - E0;
        const int per = (total + 7) >> 3;
        int i = E0 + wid * per;
        int we = i + per; we = we < E1 ? we : E1;
        int myEnd = we;
        if (i >= E1) { i = E1; myEnd = E1; }
        else {
            if (wid > 0) {
                unsigned pv = csr[i - 1];
                unsigned kp = ((pv >> 28) << 4) | (pv & 15u);
                while (i < we) {
                    unsigned cc = csr[i];
                    if ((((cc >> 28) << 4) | (cc & 15u)) != kp) break;
                    ++i;
                }
            }
            if (myEnd < E1 && myEnd > i) {
                unsigned lv = csr[myEnd - 1];
                unsigned kl = ((lv >> 28) << 4) | (lv & 15u);
                while (myEnd < E1) {
                    unsigned cc = csr[myEnd];
                    if ((((cc >> 28) << 4) | (cc & 15u)) != kl) break;
                    ++myEnd;
                }
            }
        }
        const int deg = myEnd - i;
        if (deg > 0) {
            const unsigned loff = (unsigned)(lane << 1);
            unsigned c0[8], c1[8];
            float x0[8], x1[8];
            int cur = -1;
            float acc = 0.f;

            auto loadb = [&](unsigned (&cv)[8], float (&xv)[8], int eb) {
                #pragma unroll
                for (int j = 0; j < 8; ++j) {
                    int idx = eb + j;
                    idx = idx < myEnd - 1 ? idx : myEnd - 1;
                    cv[j] = csr[idx];
                }
                #pragma unroll
                for (int j = 0; j < 8; ++j) {
                    unsigned off = (cv[j] & 0x0FFFFF80u) | loff;
                    xv[j] = bf2f(*reinterpret_cast<const unsigned short*>(
                        reinterpret_cast<const char*>(xbf_in) + off));
                }
            };
            auto accum = [&](unsigned (&cv)[8], float (&xv)[8], int m) {
                #pragma unroll
                for (int j = 0; j < 8; ++j) {
                    if (j < m) {
                        int kj = (int)(((cv[j] >> 28) << 4) | (cv[j] & 15u));
                        if (kj != cur) {
                            if (cur >= 0) S[(cur >> 4) * SROW + (cur & 15) * 64 + lane] = f2bf(acc);
                            cur = kj;
                            acc = 0.f;
                        }
                        acc += xv[j];
                    }
                }
            };

            int e0 = i;
            int m0 = deg > 8 ? 8 : deg;
            loadb(c0, x0, e0);
            for (;;) {
                int e1 = e0 + 8;
                int m1 = myEnd - e1;
                m1 = m1 > 8 ? 8 : m1;
                if (m1 > 0) loadb(c1, x1, e1);
                accum(c0, x0, m0);
                if (m1 <= 0) break;
                int e2 = e1 + 8;
                m0 = myEnd - e2;
                m0 = m0 > 8 ? 8 : m0;
                if (m0 > 0) loadb(c0, x0, e2);
                accum(c1, x1, m1);
                if (m0 <= 0) break;
                e0 = e2;
            }
            if (cur >= 0) S[(cur >> 4) * SROW + (cur & 15) * 64 + lane] = f2bf(acc);
        }
    }
    __syncthreads();

    // phase B: wave = (g, kh); K-halves of 17 kblocks; rel/self split accumulators
    const int g = wid & 3, kh = wid >> 2;
    const int t0 = kh * 17;
    const int colg = lane & 15, kg = lane >> 4;
    f32x4 accR = {0.f, 0.f, 0.f, 0.f};
    f32x4 accS = {0.f, 0.f, 0.f, 0.f};
    const unsigned short* wb = wt + (size_t)g * (NKB * 512) + (size_t)lane * 8 + (size_t)t0 * 512;
    const unsigned short* sa0 = &S[colg * SROW + kg * 8 + t0 * 32];
    if (kh == 0) {
        #pragma unroll 1
        for (int t = 0; t < 17; ++t) {
            bf16x8 b  = *reinterpret_cast<const bf16x8*>(wb + (size_t)t * 512);
            bf16x8 a0 = *reinterpret_cast<const bf16x8*>(sa0 + t * 32);
            accR = __builtin_amdgcn_mfma_f32_16x16x32_bf16(a0, b, accR, 0, 0, 0);
        }
    } else {
        #pragma unroll 1
        for (int t = 0; t < 15; ++t) {
            bf16x8 b  = *reinterpret_cast<const bf16x8*>(wb + (size_t)t * 512);
            bf16x8 a0 = *reinterpret_cast<const bf16x8*>(sa0 + t * 32);
            accR = __builtin_amdgcn_mfma_f32_16x16x32_bf16(a0, b, accR, 0, 0, 0);
        }
        #pragma unroll
        for (int t = 15; t < 17; ++t) {
            bf16x8 b  = *reinterpret_cast<const bf16x8*>(wb + (size_t)t * 512);
            bf16x8 a0 = *reinterpret_cast<const bf16x8*>(sa0 + t * 32);
            accS = __builtin_amdgcn_mfma_f32_16x16x32_bf16(a0, b, accS, 0, 0, 0);
        }
    }
    __syncthreads();
    float4* scr = reinterpret_cast<float4*>(S);
    if (kh == 1) {
        scr[g * 64 + lane]       = make_float4(accR[0], accR[1], accR[2], accR[3]);
        scr[256 + g * 64 + lane] = make_float4(accS[0], accS[1], accS[2], accS[3]);
    }
    __syncthreads();
    if (kh == 0) {
        float4 qR = scr[g * 64 + lane];
        float4 qS = scr[256 + g * 64 + lane];
        accR[0] += qR.x; accR[1] += qR.y; accR[2] += qR.z; accR[3] += qR.w;
        accS[0] += qS.x; accS[1] += qS.y; accS[2] += qS.z; accS[3] += qS.w;
        const float4 iv4 = *reinterpret_cast<const float4*>(&invs[kg * 4]);
        const float iv[4] = {iv4.x, iv4.y, iv4.z, iv4.w};
        const int col = g * 16 + colg;
        const float sb = selfb[col];
        #pragma unroll
        for (int j = 0; j < 4; ++j) {
            int n0 = nb + kg * 4 + j;
            float v0 = accR[j] * iv[j] + accS[j] + sb;
            v0 = v0 > 0.f ? v0 : 0.f;
            xbf_out[(size_t)n0 * 64 + col] = f2bf(v0);
        }
    }
}

// ---------- scoring: MFMA [8192x192]·[192x64], 16 queries/block ----------
__global__ __launch_bounds__(256) void k_score(
    const unsigned short* __restrict__ x, const int* __restrict__ heads,
    const int* __restrict__ rels, const int* __restrict__ tails,
    const unsigned short* __restrict__ reb, const unsigned short* __restrict__ w1p,
    const float* __restrict__ b1, const float* __restrict__ w2,
    const float* __restrict__ b2, float* __restrict__ out)
{
    __shared__ float scr[64];
    const int tid = threadIdx.x, lane = tid & 63, w = tid >> 6;
    const int qbase = blockIdx.x * 16;
    const int ql = lane & 15, kg = lane >> 4;
    const int q = qbase + ql;
    const unsigned short* zh = x + (size_t)heads[q] * 64 + kg * 8;
    const unsigned short* zt = x + (size_t)tails[q] * 64 + kg * 8;
    const unsigned short* re = reb + rels[q] * 64 + kg * 8;
    bf16x8 a0 = *reinterpret_cast<const bf16x8*>(zh);
    bf16x8 a1 = *reinterpret_cast<const bf16x8*>(zh + 32);
    bf16x8 a2 = *reinterpret_cast<const bf16x8*>(zt);
    bf16x8 a3 = *reinterpret_cast<const bf16x8*>(zt + 32);
    bf16x8 a4 = *reinterpret_cast<const bf16x8*>(re);
    bf16x8 a5 = *reinterpret_cast<const bf16x8*>(re + 32);
    const unsigned short* wb = w1p + (size_t)w * (6 * 512) + (size_t)lane * 8;
    f32x4 acc = {0.f, 0.f, 0.f, 0.f};
    acc = __builtin_amdgcn_mfma_f32_16x16x32_bf16(a0, *reinterpret_cast<const bf16x8*>(wb + 0 * 512), acc, 0, 0, 0);
    acc = __builtin_amdgcn_mfma_f32_16x16x32_bf16(a1, *reinterpret_cast<const bf16x8*>(wb + 1 * 512), acc, 0, 0, 0);
    acc = __builtin_amdgcn_mfma_f32_16x16x32_bf16(a2, *reinterpret_cast<const bf16x8*>(wb + 2 * 512), acc, 0, 0, 0);
    acc = __builtin_amdgcn_mfma_f32_16x16x32_bf16(a3, *reinterpret_cast<const bf16x8*>(wb + 3 * 512), acc, 0, 0, 0);
    acc = __builtin_amdgcn_mfma_f32_16x16x32_bf16(a4, *reinterpret_cast<const bf16x8*>(wb + 4 * 512), acc, 0, 0, 0);
    acc = __builtin_amdgcn_mfma_f32_16x16x32_bf16(a5, *reinterpret_cast<const bf16x8*>(wb + 5 * 512), acc, 0, 0, 0);
    const int col = w * 16 + ql;
    const float b1c = b1[col], w2c = w2[col];
    float p[4];
    #pragma unroll
    for (int j = 0; j < 4; ++j) {
        float hh = acc[j] + b1c;
        hh = hh > 0.f ? hh : 0.f;
        p[j] = hh * w2c;
    }
    #pragma unroll
    for (int o = 1; o < 16; o <<= 1) {
        p[0] += __shfl_xor(p[0], o);
        p[1] += __shfl_xor(p[1], o);
        p[2] += __shfl_xor(p[2], o);
        p[3] += __shfl_xor(p[3], o);
    }
    if (ql == 0) {
        #pragma unroll
        for (int j = 0; j < 4; ++j) scr[w * 16 + kg * 4 + j] = p[j];
    }
    __syncthreads();
    if (tid < 16)
        out[qbase + tid] = scr[tid] + scr[16 + tid] + scr[32 + tid] + scr[48 + tid] + b2[0];
}

// ---------- launch ----------
extern "C" void kernel_launch(void* const* d_in, const int* in_sizes, int n_in,
                              void* d_out, int out_size, void* d_ws, size_t ws_size,
                              hipStream_t stream)
{
    const float* node_feat = (const float*)d_in[0];
    const int* edge_index  = (const int*)d_in[1];
    const int* edge_type   = (const int*)d_in[2];
    const int* heads       = (const int*)d_in[3];
    const int* rels        = (const int*)d_in[4];
    const int* tails       = (const int*)d_in[5];
    const float* in_w      = (const float*)d_in[6];
    const float* in_b      = (const float*)d_in[7];
    const float* rel_w     = (const float*)d_in[8];
    const float* self_w    = (const float*)d_in[9];
    const float* self_b    = (const float*)d_in[10];
    const float* rel_emb   = (const float*)d_in[11];
    const float* sc_w1     = (const float*)d_in[12];
    const float* sc_b1     = (const float*)d_in[13];
    const float* sc_w2     = (const float*)d_in[14];
    const float* sc_b2     = (const float*)d_in[15];
    float* out = (float*)d_out;

    char* ws = (char*)d_ws;
    size_t off = 0;
    auto alloc = [&](size_t bytes) -> void* {
        void* p = ws + off;
        off = (off + bytes + 255) & ~(size_t)255;
        return p;
    };
    unsigned short* xbf_a = (unsigned short*)alloc((size_t)N_NODES * 64 * 2);
    unsigned short* xbf_b = (unsigned short*)alloc((size_t)N_NODES * 64 * 2);
    int* offs             = (int*)alloc((size_t)(NKEY + 1) * 4);
    unsigned int* scratch = (unsigned int*)alloc((size_t)N_EDGES * 4);
    unsigned int* csr     = (unsigned int*)alloc((size_t)N_EDGES * 4);
    unsigned short* wt    = (unsigned short*)alloc((size_t)2 * WTL * 2);
    unsigned short* w1p   = (unsigned short*)alloc((size_t)4 * 6 * 512 * 2);
    unsigned short* reb   = (unsigned short*)alloc((size_t)N_REL * 64 * 2);
    int* btot             = (int*)alloc(NBKT * 4);
    int* bbase            = (int*)alloc((NBKT + 1) * 4);
    int* gcur             = (int*)alloc(NBKT * 4);

    const int* src = edge_index;
    const int* dst = edge_index + N_EDGES;

    hipMemsetAsync(btot, 0, NBKT * 4, stream);
    k_prep<<<NB_PROJ + NB_WPREP + NB_BINA + NB_W1P + NB_REB, 256, 0, stream>>>(
        node_feat, in_w, in_b, xbf_a, rel_w, self_w, wt, dst, btot,
        sc_w1, w1p, rel_emb, reb);
    k_binS<<<1, 256, 0, stream>>>(btot, bbase, gcur);
    k_binB<<<(N_EDGES + 4095) / 4096, 256, 0, stream>>>(src, dst, edge_type, gcur, scratch);
    k_key2<<<NBKT, 1024, 0, stream>>>(bbase, scratch, offs, csr);

    for (int l = 0; l < 2; ++l) {
        const unsigned short* xin = (l == 0) ? xbf_a : xbf_b;
        unsigned short* xout = (l == 0) ? xbf_b : xbf_a;
        k_layer<<<N_NODES / TILE, 512, 0, stream>>>(
            xin, offs, csr, wt + (size_t)l * WTL, self_b + l * 64, xout);
    }
    k_score<<<N_Q / 16, 256, 0, stream>>>(xbf_a, heads, rels, tails, reb, w1p,
                                          sc_b1, sc_w2, sc_b2, out);
}

// Round 18
// 138.999 us; speedup vs baseline: 1.1005x; 1.1005x over previous
//
#include <hip/hip_runtime.h>
#include <hip/hip_bf16.h>
#include <cstdint>
#include <cstddef>

#define N_NODES 50000
#define N_EDGES 800000
#define DIM 64
#define N_REL 16
#define N_Q 8192
#define NKEY (N_NODES * 16)
#define KDIM 1088   // 16 relations * 64 + 64 self
#define SROW 1096   // padded LDS row in bf16 elems
#define TILE 16     // nodes per block (2 per wave, 8 waves)
#define NKB 34      // K blocks of 32 (KDIM/32)
#define WTL (4 * NKB * 512)  // per-layer packed wt elems
#define NBKT 196    // coarse buckets (dst>>8)

// fused-prep grid partition
#define NB_PROJ 12500            // 50000*64/256
#define NB_WPREP 544             // 2*WTL/256
#define NB_BINA 196              // ceil(N_EDGES/4096)
#define NB_W1P 48                // 4*6*512/256
#define NB_REB 4                 // 1024/256

typedef __attribute__((ext_vector_type(8))) short bf16x8;
typedef __attribute__((ext_vector_type(4))) float f32x4;

__device__ __forceinline__ unsigned short f2bf(float f) {
    unsigned int b = __float_as_uint(f);
    return (unsigned short)((b + 0x7FFFu + ((b >> 16) & 1u)) >> 16);
}
__device__ __forceinline__ float bf2f(unsigned short u) {
    return __uint_as_float(((unsigned int)u) << 16);
}

// ---------- fused prep: input proj + wt pack + coarse hist + w1 pack + rel_emb bf16 ----------
__global__ __launch_bounds__(256) void k_prep(
    const float* __restrict__ nf, const float* __restrict__ inw,
    const float* __restrict__ inb, unsigned short* __restrict__ xbf,
    const float* __restrict__ rel_w, const float* __restrict__ self_w,
    unsigned short* __restrict__ wt, const int* __restrict__ dst,
    int* __restrict__ btot, const float* __restrict__ sc_w1,
    unsigned short* __restrict__ w1p, const float* __restrict__ rel_emb,
    unsigned short* __restrict__ reb)
{
    __shared__ int h[NBKT];
    const int b = blockIdx.x, tid = threadIdx.x;
    if (b < NB_PROJ) {
        int t = b * 256 + tid;
        int n = t >> 6, o = t & 63;
        float4 f = *reinterpret_cast<const float4*>(nf + (size_t)n * 4);
        float a = inb[o] + f.x * inw[o] + f.y * inw[64 + o] + f.z * inw[128 + o] + f.w * inw[192 + o];
        xbf[t] = f2bf(a > 0.f ? a : 0.f);
    } else if (b < NB_PROJ + NB_WPREP) {
        int i = (b - NB_PROJ) * 256 + tid;
        int j = i & 7;
        int lane = (i >> 3) & 63;
        int rest = i >> 9;          // l*136 + g*34 + t
        int t = rest % NKB;
        int gl = rest / NKB;
        int g = gl & 3;
        int l = gl >> 2;
        int col = g * 16 + (lane & 15);
        int k = t * 32 + (lane >> 4) * 8 + j;
        float v;
        if (k < 1024) {
            int r = k >> 6, d = k & 63;
            v = rel_w[(((size_t)l * 16 + r) * 64 + d) * 64 + col];
        } else {
            int d = k - 1024;
            v = self_w[((size_t)l * 64 + d) * 64 + col];
        }
        wt[i] = f2bf(v);
    } else if (b < NB_PROJ + NB_WPREP + NB_BINA) {
        // coarse per-bucket histogram (btot pre-zeroed via memset)
        const int t = tid;
        if (t < NBKT) h[t] = 0;
        __syncthreads();
        const int e0 = (b - NB_PROJ - NB_WPREP) * 4096;
        #pragma unroll
        for (int j = 0; j < 16; ++j) {
            int e = e0 + j * 256 + t;
            if (e < N_EDGES) atomicAdd(&h[dst[e] >> 8], 1);
        }
        __syncthreads();
        if (t < NBKT && h[t]) atomicAdd(&btot[t], h[t]);
    } else if (b < NB_PROJ + NB_WPREP + NB_BINA + NB_W1P) {
        int i = (b - NB_PROJ - NB_WPREP - NB_BINA) * 256 + tid;  // < 12288
        int j = i & 7;
        int lane = (i >> 3) & 63;
        int rest = i >> 9;          // g*6 + t, < 24
        int t = rest % 6;
        int g = rest / 6;
        int col = g * 16 + (lane & 15);
        int k = t * 32 + (lane >> 4) * 8 + j;   // < 192
        w1p[i] = f2bf(sc_w1[k * 64 + col]);
    } else {
        int i = (b - NB_PROJ - NB_WPREP - NB_BINA - NB_W1P) * 256 + tid;
        if (i < N_REL * 64) reb[i] = f2bf(rel_emb[i]);
    }
}

// ---------- bucket pipeline ----------
__global__ __launch_bounds__(256) void k_binS(
    const int* __restrict__ btot, int* __restrict__ bbase, int* __restrict__ gcur)
{
    const int t = threadIdx.x;
    int v = (t < NBKT) ? btot[t] : 0;
    const int lane = t & 63, wid = t >> 6;
    int incl = v;
    #pragma unroll
    for (int o = 1; o < 64; o <<= 1) { int u = __shfl_up(incl, o); if (lane >= o) incl += u; }
    __shared__ int ws[4];
    if (lane == 63) ws[wid] = incl;
    __syncthreads();
    int wb = 0;
    #pragma unroll
    for (int w = 0; w < 4; ++w) if (w < wid) wb += ws[w];
    int excl = wb + incl - v;
    if (t < NBKT) { bbase[t] = excl; gcur[t] = excl; }
    if (t == NBKT - 1) bbase[NBKT] = excl + v;
}

// payload = src<<12 | (dst&255)<<4 | et
__global__ __launch_bounds__(256) void k_binB(
    const int* __restrict__ src, const int* __restrict__ dst, const int* __restrict__ et,
    int* __restrict__ gcur, unsigned int* __restrict__ scratch)
{
    __shared__ int cnt[NBKT], base[NBKT], lcur[NBKT];
    const int t = threadIdx.x;
    if (t < NBKT) cnt[t] = 0;
    __syncthreads();
    const int e0 = blockIdx.x * 4096;
    int dv[16];
    #pragma unroll
    for (int j = 0; j < 16; ++j) {
        int e = e0 + j * 256 + t;
        dv[j] = (e < N_EDGES) ? dst[e] : -1;
        if (dv[j] >= 0) atomicAdd(&cnt[dv[j] >> 8], 1);
    }
    __syncthreads();
    if (t < NBKT) {
        base[t] = cnt[t] ? atomicAdd(&gcur[t], cnt[t]) : 0;
        lcur[t] = 0;
    }
    __syncthreads();
    #pragma unroll
    for (int j = 0; j < 16; ++j) {
        int e = e0 + j * 256 + t;
        if (dv[j] >= 0) {
            int b = dv[j] >> 8;
            int pos = base[b] + atomicAdd(&lcur[b], 1);
            unsigned p = ((unsigned)src[e] << 12) | ((unsigned)(dv[j] & 255) << 4) | (unsigned)et[e];
            scratch[pos] = p;
        }
    }
}

// pass K: per bucket: fine histogram + local scan -> offs (per (node,rel) key); local scatter -> csr
// csr entry = (src<<7) | et
__global__ __launch_bounds__(1024) void k_key2(
    const int* __restrict__ bbase, const unsigned int* __restrict__ scratch,
    int* __restrict__ offs, unsigned int* __restrict__ csr)
{
    __shared__ int hist[4096];
    __shared__ int wsum[16];
    const int t = threadIdx.x;
    const int b = blockIdx.x;
    const int k0 = b * 4096;
    #pragma unroll
    for (int j = 0; j < 4; ++j) hist[t + j * 1024] = 0;
    __syncthreads();
    const int E0 = bbase[b], E1 = bbase[b + 1];
    for (int e = E0 + t; e < E1; e += 1024)
        atomicAdd(&hist[scratch[e] & 0xFFFu], 1);
    __syncthreads();
    int4 h4 = *reinterpret_cast<int4*>(&hist[t * 4]);
    int run = h4.x + h4.y + h4.z + h4.w;
    const int lane = t & 63, wid = t >> 6;
    int incl = run;
    #pragma unroll
    for (int o = 1; o < 64; o <<= 1) { int u = __shfl_up(incl, o); if (lane >= o) incl += u; }
    if (lane == 63) wsum[wid] = incl;
    __syncthreads();
    if (wid == 0) {
        int wv = (lane < 16) ? wsum[lane] : 0;
        #pragma unroll
        for (int o = 1; o < 16; o <<= 1) { int u = __shfl_up(wv, o); if (lane >= o) wv += u; }
        if (lane < 16) wsum[lane] = wv;
    }
    __syncthreads();
    int texcl = (wid ? wsum[wid - 1] : 0) + incl - run;
    int4 cur;
    cur.x = E0 + texcl;
    cur.y = cur.x + h4.x;
    cur.z = cur.y + h4.y;
    cur.w = cur.z + h4.z;
    *reinterpret_cast<int4*>(&hist[t * 4]) = cur;
    if (k0 + t * 4 < NKEY)
        *reinterpret_cast<int4*>(&offs[k0 + t * 4]) = cur;
    if (b == NBKT - 1 && t == 0) offs[NKEY] = N_EDGES;
    __syncthreads();
    for (int e = E0 + t; e < E1; e += 1024) {
        unsigned p = scratch[e];
        int pos = atomicAdd(&hist[p & 0xFFFu], 1);
        csr[pos] = ((p >> 12) << 7) | (p & 15u);
    }
}

// ---------- fused layer: 16 nodes/block, 8 waves, 4 blocks/CU ----------
__global__ __launch_bounds__(512, 8) void k_layer(
    const unsigned short* __restrict__ xbf_in,
    const int* __restrict__ offs,
    const unsigned int* __restrict__ csr,
    const unsigned short* __restrict__ wt,    // this layer, packed: [4][34][64][8] bf16
    const float* __restrict__ selfb,          // [64]
    unsigned short* __restrict__ xbf_out)
{
    alignas(16) __shared__ unsigned short S[TILE * SROW];   // 35072 B
    const int tid = threadIdx.x, lane = tid & 63;
    const int wid = __builtin_amdgcn_readfirstlane(tid >> 6);   // 0..7
    const int nb = blockIdx.x * TILE;

    #pragma unroll
    for (int s = 0; s < 2; ++s) {
        unsigned int* Sr = reinterpret_cast<unsigned int*>(&S[(wid * 2 + s) * SROW]);
        #pragma unroll
        for (int i = 0; i < 8; ++i) Sr[lane + i * 64] = 0u;
        if (lane < 32) Sr[512 + lane] = 0u;
    }

    // phase A: per-node gather, 8-deep double-buffered pipeline (proven)
    #pragma unroll 1
    for (int s = 0; s < 2; ++s) {
        const int nl = wid * 2 + s;
        const int node = nb + nl;
        const int A = offs[node * 16];
        const int B = offs[node * 16 + 16];
        S[nl * SROW + 1024 + lane] = xbf_in[(size_t)node * 64 + lane];
        const int deg = B - A;
        if (deg <= 0) continue;
        const float inv = 1.0f / (float)(deg > 1 ? deg : 1);

        const unsigned loff = (unsigned)(lane << 1);
        unsigned c0[8], c1[8];
        float x0[8], x1[8];
        int cur = -1;
        float acc = 0.f;

        auto loadb = [&](unsigned (&cv)[8], float (&xv)[8], int eb) {
            #pragma unroll
            for (int j = 0; j < 8; ++j) {
                int idx = eb + j;
                idx = idx < B - 1 ? idx : B - 1;
                cv[j] = csr[idx];
            }
            #pragma unroll
            for (int j = 0; j < 8; ++j) {
                unsigned off = (cv[j] & 0xFFFFFF80u) | loff;
                xv[j] = bf2f(*reinterpret_cast<const unsigned short*>(
                    reinterpret_cast<const char*>(xbf_in) + off));
            }
        };
        auto accum = [&](unsigned (&cv)[8], float (&xv)[8], int m) {
            #pragma unroll
            for (int j = 0; j < 8; ++j) {
                if (j < m) {
                    int rj = (int)(cv[j] & 15u);
                    if (rj != cur) {
                        if (cur >= 0) S[nl * SROW + cur * 64 + lane] = f2bf(acc * inv);
                        cur = rj;
                        acc = 0.f;
                    }
                    acc += xv[j];
                }
            }
        };

        int e0 = A;
        int m0 = deg > 8 ? 8 : deg;
        loadb(c0, x0, e0);
        for (;;) {
            int e1 = e0 + 8;
            int m1 = B - e1;
            m1 = m1 > 8 ? 8 : m1;
            if (m1 > 0) loadb(c1, x1, e1);
            accum(c0, x0, m0);
            if (m1 <= 0) break;
            int e2 = e1 + 8;
            m0 = B - e2;
            m0 = m0 > 8 ? 8 : m0;
            if (m0 > 0) loadb(c0, x0, e2);
            accum(c1, x1, m1);
            if (m0 <= 0) break;
            e0 = e2;
        }
        if (cur >= 0) S[nl * SROW + cur * 64 + lane] = f2bf(acc * inv);
    }
    __syncthreads();

    // phase B: wave = (g, kh); K-halves of 17 kblocks; one 16-node m-tile
    const int g = wid & 3, kh = wid >> 2;
    const int t0 = kh * 17;
    const int colg = lane & 15, kg = lane >> 4;
    f32x4 acc0 = {0.f, 0.f, 0.f, 0.f};
    const unsigned short* wb = wt + (size_t)g * (NKB * 512) + (size_t)lane * 8 + (size_t)t0 * 512;
    const unsigned short* sa0 = &S[colg * SROW + kg * 8 + t0 * 32];
    #pragma unroll 2
    for (int t = 0; t < 17; ++t) {
        bf16x8 b  = *reinterpret_cast<const bf16x8*>(wb + (size_t)t * 512);
        bf16x8 a0 = *reinterpret_cast<const bf16x8*>(sa0 + t * 32);
        acc0 = __builtin_amdgcn_mfma_f32_16x16x32_bf16(a0, b, acc0, 0, 0, 0);
    }
    __syncthreads();
    float4* scr = reinterpret_cast<float4*>(S);
    if (kh == 1) {
        scr[g * 64 + lane] = make_float4(acc0[0], acc0[1], acc0[2], acc0[3]);
    }
    __syncthreads();
    if (kh == 0) {
        float4 q0 = scr[g * 64 + lane];
        acc0[0] += q0.x; acc0[1] += q0.y; acc0[2] += q0.z; acc0[3] += q0.w;
        const int col = g * 16 + colg;
        const float sb = selfb[col];
        #pragma unroll
        for (int j = 0; j < 4; ++j) {
            int n0 = nb + kg * 4 + j;
            float v0 = acc0[j] + sb;
            v0 = v0 > 0.f ? v0 : 0.f;
            xbf_out[(size_t)n0 * 64 + col] = f2bf(v0);
        }
    }
}

// ---------- scoring: MFMA [8192x192]·[192x64], 16 queries/block ----------
__global__ __launch_bounds__(256) void k_score(
    const unsigned short* __restrict__ x, const int* __restrict__ heads,
    const int* __restrict__ rels, const int* __restrict__ tails,
    const unsigned short* __restrict__ reb, const unsigned short* __restrict__ w1p,
    const float* __restrict__ b1, const float* __restrict__ w2,
    const float* __restrict__ b2, float* __restrict__ out)
{
    __shared__ float scr[64];
    const int tid = threadIdx.x, lane = tid & 63, w = tid >> 6;
    const int qbase = blockIdx.x * 16;
    const int ql = lane & 15, kg = lane >> 4;
    const int q = qbase + ql;
    const unsigned short* zh = x + (size_t)heads[q] * 64 + kg * 8;
    const unsigned short* zt = x + (size_t)tails[q] * 64 + kg * 8;
    const unsigned short* re = reb + rels[q] * 64 + kg * 8;
    bf16x8 a0 = *reinterpret_cast<const bf16x8*>(zh);
    bf16x8 a1 = *reinterpret_cast<const bf16x8*>(zh + 32);
    bf16x8 a2 = *reinterpret_cast<const bf16x8*>(zt);
    bf16x8 a3 = *reinterpret_cast<const bf16x8*>(zt + 32);
    bf16x8 a4 = *reinterpret_cast<const bf16x8*>(re);
    bf16x8 a5 = *reinterpret_cast<const bf16x8*>(re + 32);
    const unsigned short* wb = w1p + (size_t)w * (6 * 512) + (size_t)lane * 8;
    f32x4 acc = {0.f, 0.f, 0.f, 0.f};
    acc = __builtin_amdgcn_mfma_f32_16x16x32_bf16(a0, *reinterpret_cast<const bf16x8*>(wb + 0 * 512), acc, 0, 0, 0);
    acc = __builtin_amdgcn_mfma_f32_16x16x32_bf16(a1, *reinterpret_cast<const bf16x8*>(wb + 1 * 512), acc, 0, 0, 0);
    acc = __builtin_amdgcn_mfma_f32_16x16x32_bf16(a2, *reinterpret_cast<const bf16x8*>(wb + 2 * 512), acc, 0, 0, 0);
    acc = __builtin_amdgcn_mfma_f32_16x16x32_bf16(a3, *reinterpret_cast<const bf16x8*>(wb + 3 * 512), acc, 0, 0, 0);
    acc = __builtin_amdgcn_mfma_f32_16x16x32_bf16(a4, *reinterpret_cast<const bf16x8*>(wb + 4 * 512), acc, 0, 0, 0);
    acc = __builtin_amdgcn_mfma_f32_16x16x32_bf16(a5, *reinterpret_cast<const bf16x8*>(wb + 5 * 512), acc, 0, 0, 0);
    const int col = w * 16 + ql;
    const float b1c = b1[col], w2c = w2[col];
    float p[4];
    #pragma unroll
    for (int j = 0; j < 4; ++j) {
        float hh = acc[j] + b1c;
        hh = hh > 0.f ? hh : 0.f;
        p[j] = hh * w2c;
    }
    #pragma unroll
    for (int o = 1; o < 16; o <<= 1) {
        p[0] += __shfl_xor(p[0], o);
        p[1] += __shfl_xor(p[1], o);
        p[2] += __shfl_xor(p[2], o);
        p[3] += __shfl_xor(p[3], o);
    }
    if (ql == 0) {
        #pragma unroll
        for (int j = 0; j < 4; ++j) scr[w * 16 + kg * 4 + j] = p[j];
    }
    __syncthreads();
    if (tid < 16)
        out[qbase + tid] = scr[tid] + scr[16 + tid] + scr[32 + tid] + scr[48 + tid] + b2[0];
}

// ---------- launch ----------
extern "C" void kernel_launch(void* const* d_in, const int* in_sizes, int n_in,
                              void* d_out, int out_size, void* d_ws, size_t ws_size,
                              hipStream_t stream)
{
    const float* node_feat = (const float*)d_in[0];
    const int* edge_index  = (const int*)d_in[1];
    const int* edge_type   = (const int*)d_in[2];
    const int* heads       = (const int*)d_in[3];
    const int* rels        = (const int*)d_in[4];
    const int* tails       = (const int*)d_in[5];
    const float* in_w      = (const float*)d_in[6];
    const float* in_b      = (const float*)d_in[7];
    const float* rel_w     = (const float*)d_in[8];
    const float* self_w    = (const float*)d_in[9];
    const float* self_b    = (const float*)d_in[10];
    const float* rel_emb   = (const float*)d_in[11];
    const float* sc_w1     = (const float*)d_in[12];
    const float* sc_b1     = (const float*)d_in[13];
    const float* sc_w2     = (const float*)d_in[14];
    const float* sc_b2     = (const float*)d_in[15];
    float* out = (float*)d_out;

    char* ws = (char*)d_ws;
    size_t off = 0;
    auto alloc = [&](size_t bytes) -> void* {
        void* p = ws + off;
        off = (off + bytes + 255) & ~(size_t)255;
        return p;
    };
    unsigned short* xbf_a = (unsigned short*)alloc((size_t)N_NODES * 64 * 2);
    unsigned short* xbf_b = (unsigned short*)alloc((size_t)N_NODES * 64 * 2);
    int* offs             = (int*)alloc((size_t)(NKEY + 1) * 4);
    unsigned int* scratch = (unsigned int*)alloc((size_t)N_EDGES * 4);
    unsigned int* csr     = (unsigned int*)alloc((size_t)N_EDGES * 4);
    unsigned short* wt    = (unsigned short*)alloc((size_t)2 * WTL * 2);
    unsigned short* w1p   = (unsigned short*)alloc((size_t)4 * 6 * 512 * 2);
    unsigned short* reb   = (unsigned short*)alloc((size_t)N_REL * 64 * 2);
    int* btot             = (int*)alloc(NBKT * 4);
    int* bbase            = (int*)alloc((NBKT + 1) * 4);
    int* gcur             = (int*)alloc(NBKT * 4);

    const int* src = edge_index;
    const int* dst = edge_index + N_EDGES;

    hipMemsetAsync(btot, 0, NBKT * 4, stream);
    k_prep<<<NB_PROJ + NB_WPREP + NB_BINA + NB_W1P + NB_REB, 256, 0, stream>>>(
        node_feat, in_w, in_b, xbf_a, rel_w, self_w, wt, dst, btot,
        sc_w1, w1p, rel_emb, reb);
    k_binS<<<1, 256, 0, stream>>>(btot, bbase, gcur);
    k_binB<<<(N_EDGES + 4095) / 4096, 256, 0, stream>>>(src, dst, edge_type, gcur, scratch);
    k_key2<<<NBKT, 1024, 0, stream>>>(bbase, scratch, offs, csr);

    for (int l = 0; l < 2; ++l) {
        const unsigned short* xin = (l == 0) ? xbf_a : xbf_b;
        unsigned short* xout = (l == 0) ? xbf_b : xbf_a;
        k_layer<<<N_NODES / TILE, 512, 0, stream>>>(
            xin, offs, csr, wt + (size_t)l * WTL, self_b + l * 64, xout);
    }
    k_score<<<N_Q / 16, 256, 0, stream>>>(xbf_a, heads, rels, tails, reb, w1p,
                                          sc_b1, sc_w2, sc_b2, out);
}